// Round 3
// baseline (963.240 us; speedup 1.0000x reference)
//
#include <hip/hip_runtime.h>
#include <cstddef>

#define N_NODES 65536
#define NPER    1024
#define NGRAPH  64
#define HID     64
#define IN_F    128
#define KCLUS   16
#define NCLS    10
#define ECAP    18432   // per-graph edge capacity; E/NGRAPH = 16384 avg, sigma ~124

// ---------------------------------------------------------------- bucket edges by graph
// Packs each edge as (dst_local<<10)|src_local into per-graph segments of gedges.
__global__ __launch_bounds__(256) void bucket_kernel(const int* __restrict__ src,
                                                     const int* __restrict__ dst,
                                                     int* __restrict__ ecnt,
                                                     int* __restrict__ gedges, int E) {
    __shared__ int hist[NGRAPH];
    __shared__ int base_l[NGRAPH];
    const int t = threadIdx.x;
    const int e0 = blockIdx.x * 1024;
    if (t < NGRAPH) hist[t] = 0;
    __syncthreads();

    int gg[4], rr[4], pk[4];
#pragma unroll
    for (int i = 0; i < 4; ++i) {
        int idx = e0 + i * 256 + t;
        if (idx < E) {
            int d = dst[idx], s = src[idx];
            int g = d >> 10;
            gg[i] = g;
            pk[i] = ((d & 1023) << 10) | (s & 1023);
            rr[i] = atomicAdd(&hist[g], 1);   // LDS atomic w/ return: local rank
        } else gg[i] = -1;
    }
    __syncthreads();
    if (t < NGRAPH) base_l[t] = atomicAdd(&ecnt[t], hist[t]);  // 64 global atomics/block
    __syncthreads();
#pragma unroll
    for (int i = 0; i < 4; ++i) {
        if (gg[i] >= 0) {
            int pos = base_l[gg[i]] + rr[i];
            if (pos < ECAP) gedges[gg[i] * ECAP + pos] = pk[i];
        }
    }
}

// ---------------------------------------------------------------- per-graph degree -> dinv (LDS histogram, no global atomics)
__global__ __launch_bounds__(256) void degdinv_kernel(const int* __restrict__ gedges,
                                                      const int* __restrict__ ecnt,
                                                      float* __restrict__ dinv) {
    __shared__ int hist[NPER];
    const int g = blockIdx.x, t = threadIdx.x;
    for (int i = t; i < NPER; i += 256) hist[i] = 0;
    __syncthreads();
    const int ec = ecnt[g];
    const int* ge = gedges + (size_t)g * ECAP;
    for (int i = t; i < ec; i += 256) atomicAdd(&hist[ge[i] >> 10], 1);
    __syncthreads();
    for (int i = t; i < NPER; i += 256)
        dinv[g * NPER + i] = rsqrtf((float)hist[i] + 1.0f);
}

// ---------------------------------------------------------------- dense linear: Y[N,64] = X[N,K] @ W[64,K]^T
template <int K>
__global__ __launch_bounds__(256) void linear_kernel(const float* __restrict__ X,
                                                     const float* __restrict__ W,
                                                     float* __restrict__ Y) {
    __shared__ float xs[64][K + 1];
    __shared__ float ws[HID][K + 1];
    const int t = threadIdx.x;
    const size_t row0 = (size_t)blockIdx.x * 64;

    for (int i = t; i < HID * K; i += 256) ws[i / K][i % K] = W[i];
    for (int i = t; i < 64 * K; i += 256) xs[i / K][i % K] = X[row0 * K + i];
    __syncthreads();

    const int r0 = (t >> 4) * 4;
    const int c0 = (t & 15) * 4;
    float acc[4][4] = {};

#pragma unroll 4
    for (int k = 0; k < K; ++k) {
        float xv0 = xs[r0 + 0][k], xv1 = xs[r0 + 1][k];
        float xv2 = xs[r0 + 2][k], xv3 = xs[r0 + 3][k];
        float wv0 = ws[c0 + 0][k], wv1 = ws[c0 + 1][k];
        float wv2 = ws[c0 + 2][k], wv3 = ws[c0 + 3][k];
        acc[0][0] = fmaf(xv0, wv0, acc[0][0]);
        acc[0][1] = fmaf(xv0, wv1, acc[0][1]);
        acc[0][2] = fmaf(xv0, wv2, acc[0][2]);
        acc[0][3] = fmaf(xv0, wv3, acc[0][3]);
        acc[1][0] = fmaf(xv1, wv0, acc[1][0]);
        acc[1][1] = fmaf(xv1, wv1, acc[1][1]);
        acc[1][2] = fmaf(xv1, wv2, acc[1][2]);
        acc[1][3] = fmaf(xv1, wv3, acc[1][3]);
        acc[2][0] = fmaf(xv2, wv0, acc[2][0]);
        acc[2][1] = fmaf(xv2, wv1, acc[2][1]);
        acc[2][2] = fmaf(xv2, wv2, acc[2][2]);
        acc[2][3] = fmaf(xv2, wv3, acc[2][3]);
        acc[3][0] = fmaf(xv3, wv0, acc[3][0]);
        acc[3][1] = fmaf(xv3, wv1, acc[3][1]);
        acc[3][2] = fmaf(xv3, wv2, acc[3][2]);
        acc[3][3] = fmaf(xv3, wv3, acc[3][3]);
    }

#pragma unroll
    for (int i = 0; i < 4; ++i) {
        float4 v = make_float4(acc[i][0], acc[i][1], acc[i][2], acc[i][3]);
        *(float4*)(Y + (row0 + r0 + i) * HID + c0) = v;
    }
}

// ---------------------------------------------------------------- push-based aggregation via LDS atomics
// grid = NGRAPH * 8; block (g, fq) handles feats [fq*8, fq*8+8) of graph g.
// Hs[j][s] = h[base+s][f0+j] * dinv[base+s]; Acc accumulated with ds_add_f32.
__global__ __launch_bounds__(256) void agg_kernel(const float* __restrict__ h,
                                                  const int* __restrict__ gedges,
                                                  const int* __restrict__ ecnt,
                                                  const float* __restrict__ dinv,
                                                  const float* __restrict__ bias,
                                                  float* __restrict__ outp) {
    __shared__ float Hs[8][NPER + 1];
    __shared__ float Acc[8][NPER + 1];
    __shared__ float dl[NPER];
    const int g = blockIdx.x >> 3;
    const int f0 = (blockIdx.x & 7) * 8;
    const int t = threadIdx.x;
    const int base = g * NPER;

    for (int r = t; r < NPER; r += 256) {
        const float* hp = h + (size_t)(base + r) * HID + f0;
        float4 a = *(const float4*)hp;
        float4 b = *(const float4*)(hp + 4);
        float dv = dinv[base + r];
        dl[r] = dv;
        Hs[0][r] = a.x * dv; Hs[1][r] = a.y * dv; Hs[2][r] = a.z * dv; Hs[3][r] = a.w * dv;
        Hs[4][r] = b.x * dv; Hs[5][r] = b.y * dv; Hs[6][r] = b.z * dv; Hs[7][r] = b.w * dv;
#pragma unroll
        for (int j = 0; j < 8; ++j) Acc[j][r] = 0.f;
    }
    float bb[8];
#pragma unroll
    for (int j = 0; j < 8; ++j) bb[j] = bias[f0 + j];
    const int ec = ecnt[g];
    const int* ge = gedges + (size_t)g * ECAP;
    __syncthreads();

    for (int i = t; i < ec; i += 256) {
        int p = ge[i];
        int sl = p & 1023;
        int dd = p >> 10;
#pragma unroll
        for (int j = 0; j < 8; ++j) atomicAdd(&Acc[j][dd], Hs[j][sl]);  // ds_add_f32
    }
    __syncthreads();

    for (int r = t; r < NPER; r += 256) {
        const float dv = dl[r];
        float4 o0, o1;
        o0.x = fmaxf(fmaf(Acc[0][r] + Hs[0][r], dv, bb[0]), 0.f);
        o0.y = fmaxf(fmaf(Acc[1][r] + Hs[1][r], dv, bb[1]), 0.f);
        o0.z = fmaxf(fmaf(Acc[2][r] + Hs[2][r], dv, bb[2]), 0.f);
        o0.w = fmaxf(fmaf(Acc[3][r] + Hs[3][r], dv, bb[3]), 0.f);
        o1.x = fmaxf(fmaf(Acc[4][r] + Hs[4][r], dv, bb[4]), 0.f);
        o1.y = fmaxf(fmaf(Acc[5][r] + Hs[5][r], dv, bb[5]), 0.f);
        o1.z = fmaxf(fmaf(Acc[6][r] + Hs[6][r], dv, bb[6]), 0.f);
        o1.w = fmaxf(fmaf(Acc[7][r] + Hs[7][r], dv, bb[7]), 0.f);
        float* op = outp + (size_t)(base + r) * HID + f0;
        *(float4*)op = o0;
        *(float4*)(op + 4) = o1;
    }
}

// ---------------------------------------------------------------- DMoN assignment: s = softmax(h @ Wp^T + bp)
__global__ __launch_bounds__(256) void assign_kernel(const float* __restrict__ h,
                                                     const float* __restrict__ Wp,
                                                     const float* __restrict__ bp,
                                                     float* __restrict__ s) {
    __shared__ float hs[256][65];
    __shared__ float wp[KCLUS][HID];
    __shared__ float bps[KCLUS];
    const int t = threadIdx.x;
    const size_t node0 = (size_t)blockIdx.x * 256;

    for (int i = t; i < 256 * HID; i += 256) hs[i >> 6][i & 63] = h[node0 * HID + i];
    for (int i = t; i < KCLUS * HID; i += 256) wp[i >> 6][i & 63] = Wp[i];
    if (t < KCLUS) bps[t] = bp[t];
    __syncthreads();

    float lg[KCLUS];
    float mx = -1e30f;
#pragma unroll
    for (int k = 0; k < KCLUS; ++k) {
        float a = bps[k];
#pragma unroll 8
        for (int hh = 0; hh < HID; ++hh) a = fmaf(hs[t][hh], wp[k][hh], a);
        lg[k] = a;
        mx = fmaxf(mx, a);
    }
    float sum = 0.f;
#pragma unroll
    for (int k = 0; k < KCLUS; ++k) {
        lg[k] = __expf(lg[k] - mx);
        sum += lg[k];
    }
    float inv = 1.0f / sum;
    float4* sp = (float4*)(s + (node0 + t) * KCLUS);
#pragma unroll
    for (int k = 0; k < KCLUS; k += 4)
        sp[k >> 2] = make_float4(lg[k] * inv, lg[k + 1] * inv, lg[k + 2] * inv, lg[k + 3] * inv);
}

// ---------------------------------------------------------------- per-graph pool: Xp = selu(s^T @ Xb); mean_k; @ Wl^T + bl
__global__ __launch_bounds__(256) void pool_kernel(const float* __restrict__ h,
                                                   const float* __restrict__ s,
                                                   const float* __restrict__ Wl,
                                                   const float* __restrict__ bl,
                                                   float* __restrict__ out) {
    __shared__ float xs[256][65];
    __shared__ float ss[256][17];
    __shared__ float xp[KCLUS][65];
    __shared__ float outm[HID];
    const int b = blockIdx.x;
    const int t = threadIdx.x;
    const float* hb = h + (size_t)b * NPER * HID;
    const float* sb = s + (size_t)b * NPER * KCLUS;
    const int hcol = t & 63;
    const int k0 = (t >> 6) * 4;

    float acc0 = 0.f, acc1 = 0.f, acc2 = 0.f, acc3 = 0.f;
    for (int chunk = 0; chunk < NPER / 256; ++chunk) {
        __syncthreads();
        const int nb = chunk * 256;
        for (int i = t; i < 256 * HID; i += 256) xs[i >> 6][i & 63] = hb[(size_t)nb * HID + i];
        for (int i = t; i < 256 * KCLUS; i += 256) ss[i >> 4][i & 15] = sb[(size_t)nb * KCLUS + i];
        __syncthreads();
#pragma unroll 8
        for (int n = 0; n < 256; ++n) {
            float xv = xs[n][hcol];
            acc0 = fmaf(ss[n][k0 + 0], xv, acc0);
            acc1 = fmaf(ss[n][k0 + 1], xv, acc1);
            acc2 = fmaf(ss[n][k0 + 2], xv, acc2);
            acc3 = fmaf(ss[n][k0 + 3], xv, acc3);
        }
    }

    const float sc = 1.0507009873554805f, al = 1.6732632423543772f;
    auto selu = [&](float v) { return v > 0.f ? sc * v : sc * al * (__expf(v) - 1.f); };
    xp[k0 + 0][hcol] = selu(acc0);
    xp[k0 + 1][hcol] = selu(acc1);
    xp[k0 + 2][hcol] = selu(acc2);
    xp[k0 + 3][hcol] = selu(acc3);
    __syncthreads();

    if (t < HID) {
        float m = 0.f;
#pragma unroll
        for (int k = 0; k < KCLUS; ++k) m += xp[k][t];
        outm[t] = m * (1.0f / KCLUS);
    }
    __syncthreads();

    if (t < NCLS) {
        float a = bl[t];
#pragma unroll 8
        for (int hh = 0; hh < HID; ++hh) a = fmaf(outm[hh], Wl[t * HID + hh], a);
        out[b * NCLS + t] = a;
    }
}

// ---------------------------------------------------------------- launch
extern "C" void kernel_launch(void* const* d_in, const int* in_sizes, int n_in,
                              void* d_out, int out_size, void* d_ws, size_t ws_size,
                              hipStream_t stream) {
    const float* x  = (const float*)d_in[0];
    const int* eidx = (const int*)d_in[1];
    const float* W1 = (const float*)d_in[3];
    const float* b1 = (const float*)d_in[4];
    const float* W2 = (const float*)d_in[5];
    const float* b2 = (const float*)d_in[6];
    const float* Wp = (const float*)d_in[7];
    const float* bp = (const float*)d_in[8];
    const float* Wl = (const float*)d_in[9];
    const float* bl = (const float*)d_in[10];
    float* out = (float*)d_out;

    const int E = in_sizes[1] / 2;
    const int* src = eidx;
    const int* dst = eidx + E;

    // workspace layout: ecnt | gedges | dinv | A | Bf | S
    char* w = (char*)d_ws;
    int*   ecnt   = (int*)w;   w += 256;
    int*   gedges = (int*)w;   w += (size_t)NGRAPH * ECAP * 4;
    float* dinv   = (float*)w; w += (size_t)N_NODES * 4;
    float* A      = (float*)w; w += (size_t)N_NODES * HID * 4;
    float* Bf     = (float*)w; w += (size_t)N_NODES * HID * 4;
    float* S      = (float*)w;

    hipMemsetAsync(ecnt, 0, 256, stream);
    bucket_kernel<<<(E + 1023) / 1024, 256, 0, stream>>>(src, dst, ecnt, gedges, E);
    degdinv_kernel<<<NGRAPH, 256, 0, stream>>>(gedges, ecnt, dinv);

    // conv1
    linear_kernel<IN_F><<<N_NODES / 64, 256, 0, stream>>>(x, W1, A);
    agg_kernel<<<NGRAPH * 8, 256, 0, stream>>>(A, gedges, ecnt, dinv, b1, Bf);

    // conv2
    linear_kernel<HID><<<N_NODES / 64, 256, 0, stream>>>(Bf, W2, A);
    agg_kernel<<<NGRAPH * 8, 256, 0, stream>>>(A, gedges, ecnt, dinv, b2, Bf);

    // DMoN pooling + classifier
    assign_kernel<<<N_NODES / 256, 256, 0, stream>>>(Bf, Wp, bp, S);
    pool_kernel<<<NGRAPH, 256, 0, stream>>>(Bf, S, Wl, bl, out);
}

// Round 4
// 340.593 us; speedup vs baseline: 2.8281x; 2.8281x over previous
//
#include <hip/hip_runtime.h>
#include <cstddef>

#define N_NODES 65536
#define NPER    1024
#define NGRAPH  64
#define HID     64
#define IN_F    128
#define KCLUS   16
#define NCLS    10
#define ECAP    18432   // per-graph edge capacity; E/NGRAPH = 16384 avg, +16 sigma

// ---------------------------------------------------------------- bucket edges by graph
// Packs each edge as (dst_local<<10)|src_local into per-graph segments of gedges.
__global__ __launch_bounds__(256) void bucket_kernel(const int* __restrict__ src,
                                                     const int* __restrict__ dst,
                                                     int* __restrict__ ecnt,
                                                     int* __restrict__ gedges, int E) {
    __shared__ int hist[NGRAPH];
    __shared__ int base_l[NGRAPH];
    const int t = threadIdx.x;
    const int e0 = blockIdx.x * 1024;
    if (t < NGRAPH) hist[t] = 0;
    __syncthreads();

    int gg[4], rr[4], pk[4];
#pragma unroll
    for (int i = 0; i < 4; ++i) {
        int idx = e0 + i * 256 + t;
        if (idx < E) {
            int d = dst[idx], s = src[idx];
            int g = d >> 10;
            gg[i] = g;
            pk[i] = ((d & 1023) << 10) | (s & 1023);
            rr[i] = atomicAdd(&hist[g], 1);   // LDS atomic w/ return: local rank
        } else gg[i] = -1;
    }
    __syncthreads();
    if (t < NGRAPH) base_l[t] = atomicAdd(&ecnt[t], hist[t]);  // 64 global atomics/block
    __syncthreads();
#pragma unroll
    for (int i = 0; i < 4; ++i) {
        if (gg[i] >= 0) {
            int pos = base_l[gg[i]] + rr[i];
            if (pos < ECAP) gedges[gg[i] * ECAP + pos] = pk[i];
        }
    }
}

// ---------------------------------------------------------------- per-graph CSR build in LDS
// One block per graph: hist(dst) -> scan -> rp + dinv; rank-scatter src_local (ushort).
__global__ __launch_bounds__(256) void csr_kernel(const int* __restrict__ gedges,
                                                  const int* __restrict__ ecnt,
                                                  int* __restrict__ rp,
                                                  unsigned short* __restrict__ esorted,
                                                  float* __restrict__ dinv) {
    __shared__ int hist[NPER];
    __shared__ int ts[256];
    const int g = blockIdx.x, t = threadIdx.x;
    const int ec = ecnt[g];
    const int* ge = gedges + (size_t)g * ECAP;

    for (int i = t; i < NPER; i += 256) hist[i] = 0;
    __syncthreads();
    for (int i = t; i < ec; i += 256) atomicAdd(&hist[ge[i] >> 10], 1);
    __syncthreads();

    // each thread owns 4 consecutive bins
    const int b0 = t * 4;
    int h0 = hist[b0], h1 = hist[b0 + 1], h2 = hist[b0 + 2], h3 = hist[b0 + 3];
    int s0 = h0, s1 = s0 + h1, s2 = s1 + h2, s3 = s2 + h3;
    ts[t] = s3;
    __syncthreads();
    for (int off = 1; off < 256; off <<= 1) {
        int x = (t >= off) ? ts[t - off] : 0;
        __syncthreads();
        ts[t] += x;
        __syncthreads();
    }
    int excl = (t > 0) ? ts[t - 1] : 0;

    // global row pointers (exclusive scan; [NPER] entry = total)
    int4 o = make_int4(excl, excl + s0, excl + s1, excl + s2);
    *(int4*)(rp + g * (NPER + 1) + b0) = o;
    if (t == 255) rp[g * (NPER + 1) + NPER] = ts[255];

    // dinv (deg + 1 self-loop)
    float4 dv;
    dv.x = rsqrtf((float)h0 + 1.0f);
    dv.y = rsqrtf((float)h1 + 1.0f);
    dv.z = rsqrtf((float)h2 + 1.0f);
    dv.w = rsqrtf((float)h3 + 1.0f);
    *(float4*)(dinv + g * NPER + b0) = dv;

    // reuse hist as scatter cursor
    hist[b0] = excl; hist[b0 + 1] = excl + s0; hist[b0 + 2] = excl + s1; hist[b0 + 3] = excl + s2;
    __syncthreads();

    unsigned short* es = esorted + (size_t)g * ECAP;
    for (int i = t; i < ec; i += 256) {
        int pk = ge[i];
        int pos = atomicAdd(&hist[pk >> 10], 1);
        es[pos] = (unsigned short)(pk & 1023);
    }
}

// ---------------------------------------------------------------- dense linear: Y[N,64] = X[N,K] @ W[64,K]^T
template <int K>
__global__ __launch_bounds__(256) void linear_kernel(const float* __restrict__ X,
                                                     const float* __restrict__ W,
                                                     float* __restrict__ Y) {
    __shared__ float xs[64][K + 1];
    __shared__ float ws[HID][K + 1];
    const int t = threadIdx.x;
    const size_t row0 = (size_t)blockIdx.x * 64;

    for (int i = t; i < HID * K; i += 256) ws[i / K][i % K] = W[i];
    for (int i = t; i < 64 * K; i += 256) xs[i / K][i % K] = X[row0 * K + i];
    __syncthreads();

    const int r0 = (t >> 4) * 4;
    const int c0 = (t & 15) * 4;
    float acc[4][4] = {};

#pragma unroll 4
    for (int k = 0; k < K; ++k) {
        float xv0 = xs[r0 + 0][k], xv1 = xs[r0 + 1][k];
        float xv2 = xs[r0 + 2][k], xv3 = xs[r0 + 3][k];
        float wv0 = ws[c0 + 0][k], wv1 = ws[c0 + 1][k];
        float wv2 = ws[c0 + 2][k], wv3 = ws[c0 + 3][k];
        acc[0][0] = fmaf(xv0, wv0, acc[0][0]);
        acc[0][1] = fmaf(xv0, wv1, acc[0][1]);
        acc[0][2] = fmaf(xv0, wv2, acc[0][2]);
        acc[0][3] = fmaf(xv0, wv3, acc[0][3]);
        acc[1][0] = fmaf(xv1, wv0, acc[1][0]);
        acc[1][1] = fmaf(xv1, wv1, acc[1][1]);
        acc[1][2] = fmaf(xv1, wv2, acc[1][2]);
        acc[1][3] = fmaf(xv1, wv3, acc[1][3]);
        acc[2][0] = fmaf(xv2, wv0, acc[2][0]);
        acc[2][1] = fmaf(xv2, wv1, acc[2][1]);
        acc[2][2] = fmaf(xv2, wv2, acc[2][2]);
        acc[2][3] = fmaf(xv2, wv3, acc[2][3]);
        acc[3][0] = fmaf(xv3, wv0, acc[3][0]);
        acc[3][1] = fmaf(xv3, wv1, acc[3][1]);
        acc[3][2] = fmaf(xv3, wv2, acc[3][2]);
        acc[3][3] = fmaf(xv3, wv3, acc[3][3]);
    }

#pragma unroll
    for (int i = 0; i < 4; ++i) {
        float4 v = make_float4(acc[i][0], acc[i][1], acc[i][2], acc[i][3]);
        *(float4*)(Y + (row0 + r0 + i) * HID + c0) = v;
    }
}

// ---------------------------------------------------------------- pull-based aggregation, fused self-loop+bias+relu
// grid = NGRAPH * 8; block (g, fq) handles feats [fq*8, fq*8+8) of graph g.
__global__ __launch_bounds__(256) void agg_kernel(const float* __restrict__ h,
                                                  const unsigned short* __restrict__ esorted,
                                                  const int* __restrict__ rp,
                                                  const float* __restrict__ dinv,
                                                  const float* __restrict__ bias,
                                                  float* __restrict__ outp) {
    __shared__ float Hs[8][NPER + 1];
    __shared__ float dl[NPER];
    const int g = blockIdx.x >> 3;
    const int f0 = (blockIdx.x & 7) * 8;
    const int t = threadIdx.x;
    const int base = g * NPER;

    for (int r = t; r < NPER; r += 256) {
        const float* hp = h + (size_t)(base + r) * HID + f0;
        float4 a = *(const float4*)hp;
        float4 b = *(const float4*)(hp + 4);
        float dv = dinv[base + r];
        dl[r] = dv;
        Hs[0][r] = a.x * dv; Hs[1][r] = a.y * dv; Hs[2][r] = a.z * dv; Hs[3][r] = a.w * dv;
        Hs[4][r] = b.x * dv; Hs[5][r] = b.y * dv; Hs[6][r] = b.z * dv; Hs[7][r] = b.w * dv;
    }
    float bb[8];
#pragma unroll
    for (int j = 0; j < 8; ++j) bb[j] = bias[f0 + j];
    const unsigned short* es = esorted + (size_t)g * ECAP;
    const int* rpg = rp + g * (NPER + 1);
    __syncthreads();

    for (int ld = t; ld < NPER; ld += 256) {
        int p = rpg[ld];
        const int pe = rpg[ld + 1];
        float acc[8];
#pragma unroll
        for (int j = 0; j < 8; ++j) acc[j] = Hs[j][ld];  // self-loop term
        for (; p < pe; ++p) {
            int sl = es[p];
#pragma unroll
            for (int j = 0; j < 8; ++j) acc[j] += Hs[j][sl];
        }
        const float dv = dl[ld];
        float4 o0, o1;
        o0.x = fmaxf(fmaf(acc[0], dv, bb[0]), 0.f);
        o0.y = fmaxf(fmaf(acc[1], dv, bb[1]), 0.f);
        o0.z = fmaxf(fmaf(acc[2], dv, bb[2]), 0.f);
        o0.w = fmaxf(fmaf(acc[3], dv, bb[3]), 0.f);
        o1.x = fmaxf(fmaf(acc[4], dv, bb[4]), 0.f);
        o1.y = fmaxf(fmaf(acc[5], dv, bb[5]), 0.f);
        o1.z = fmaxf(fmaf(acc[6], dv, bb[6]), 0.f);
        o1.w = fmaxf(fmaf(acc[7], dv, bb[7]), 0.f);
        float* op = outp + (size_t)(base + ld) * HID + f0;
        *(float4*)op = o0;
        *(float4*)(op + 4) = o1;
    }
}

// ---------------------------------------------------------------- DMoN assignment: s = softmax(h @ Wp^T + bp)
__global__ __launch_bounds__(256) void assign_kernel(const float* __restrict__ h,
                                                     const float* __restrict__ Wp,
                                                     const float* __restrict__ bp,
                                                     float* __restrict__ s) {
    __shared__ float hs[256][65];
    __shared__ float wp[KCLUS][HID];
    __shared__ float bps[KCLUS];
    const int t = threadIdx.x;
    const size_t node0 = (size_t)blockIdx.x * 256;

    for (int i = t; i < 256 * HID; i += 256) hs[i >> 6][i & 63] = h[node0 * HID + i];
    for (int i = t; i < KCLUS * HID; i += 256) wp[i >> 6][i & 63] = Wp[i];
    if (t < KCLUS) bps[t] = bp[t];
    __syncthreads();

    float lg[KCLUS];
    float mx = -1e30f;
#pragma unroll
    for (int k = 0; k < KCLUS; ++k) {
        float a = bps[k];
#pragma unroll 8
        for (int hh = 0; hh < HID; ++hh) a = fmaf(hs[t][hh], wp[k][hh], a);
        lg[k] = a;
        mx = fmaxf(mx, a);
    }
    float sum = 0.f;
#pragma unroll
    for (int k = 0; k < KCLUS; ++k) {
        lg[k] = __expf(lg[k] - mx);
        sum += lg[k];
    }
    float inv = 1.0f / sum;
    float4* sp = (float4*)(s + (node0 + t) * KCLUS);
#pragma unroll
    for (int k = 0; k < KCLUS; k += 4)
        sp[k >> 2] = make_float4(lg[k] * inv, lg[k + 1] * inv, lg[k + 2] * inv, lg[k + 3] * inv);
}

// ---------------------------------------------------------------- per-graph pool: Xp = selu(s^T @ Xb); mean_k; @ Wl^T + bl
__global__ __launch_bounds__(256) void pool_kernel(const float* __restrict__ h,
                                                   const float* __restrict__ s,
                                                   const float* __restrict__ Wl,
                                                   const float* __restrict__ bl,
                                                   float* __restrict__ out) {
    __shared__ float xs[256][65];
    __shared__ float ss[256][17];
    __shared__ float xp[KCLUS][65];
    __shared__ float outm[HID];
    const int b = blockIdx.x;
    const int t = threadIdx.x;
    const float* hb = h + (size_t)b * NPER * HID;
    const float* sb = s + (size_t)b * NPER * KCLUS;
    const int hcol = t & 63;
    const int k0 = (t >> 6) * 4;

    float acc0 = 0.f, acc1 = 0.f, acc2 = 0.f, acc3 = 0.f;
    for (int chunk = 0; chunk < NPER / 256; ++chunk) {
        __syncthreads();
        const int nb = chunk * 256;
        for (int i = t; i < 256 * HID; i += 256) xs[i >> 6][i & 63] = hb[(size_t)nb * HID + i];
        for (int i = t; i < 256 * KCLUS; i += 256) ss[i >> 4][i & 15] = sb[(size_t)nb * KCLUS + i];
        __syncthreads();
#pragma unroll 8
        for (int n = 0; n < 256; ++n) {
            float xv = xs[n][hcol];
            acc0 = fmaf(ss[n][k0 + 0], xv, acc0);
            acc1 = fmaf(ss[n][k0 + 1], xv, acc1);
            acc2 = fmaf(ss[n][k0 + 2], xv, acc2);
            acc3 = fmaf(ss[n][k0 + 3], xv, acc3);
        }
    }

    const float sc = 1.0507009873554805f, al = 1.6732632423543772f;
    auto selu = [&](float v) { return v > 0.f ? sc * v : sc * al * (__expf(v) - 1.f); };
    xp[k0 + 0][hcol] = selu(acc0);
    xp[k0 + 1][hcol] = selu(acc1);
    xp[k0 + 2][hcol] = selu(acc2);
    xp[k0 + 3][hcol] = selu(acc3);
    __syncthreads();

    if (t < HID) {
        float m = 0.f;
#pragma unroll
        for (int k = 0; k < KCLUS; ++k) m += xp[k][t];
        outm[t] = m * (1.0f / KCLUS);
    }
    __syncthreads();

    if (t < NCLS) {
        float a = bl[t];
#pragma unroll 8
        for (int hh = 0; hh < HID; ++hh) a = fmaf(outm[hh], Wl[t * HID + hh], a);
        out[b * NCLS + t] = a;
    }
}

// ---------------------------------------------------------------- launch
extern "C" void kernel_launch(void* const* d_in, const int* in_sizes, int n_in,
                              void* d_out, int out_size, void* d_ws, size_t ws_size,
                              hipStream_t stream) {
    const float* x  = (const float*)d_in[0];
    const int* eidx = (const int*)d_in[1];
    const float* W1 = (const float*)d_in[3];
    const float* b1 = (const float*)d_in[4];
    const float* W2 = (const float*)d_in[5];
    const float* b2 = (const float*)d_in[6];
    const float* Wp = (const float*)d_in[7];
    const float* bp = (const float*)d_in[8];
    const float* Wl = (const float*)d_in[9];
    const float* bl = (const float*)d_in[10];
    float* out = (float*)d_out;

    const int E = in_sizes[1] / 2;
    const int* src = eidx;
    const int* dst = eidx + E;

    // workspace layout: ecnt | gedges | esorted | rp | dinv | A | Bf | S
    char* w = (char*)d_ws;
    int*            ecnt    = (int*)w;            w += 256;
    int*            gedges  = (int*)w;            w += (size_t)NGRAPH * ECAP * 4;
    unsigned short* esorted = (unsigned short*)w; w += (size_t)NGRAPH * ECAP * 2;
    int*            rp      = (int*)w;            w += (size_t)NGRAPH * (NPER + 1) * 4;
    float*          dinv    = (float*)w;          w += (size_t)N_NODES * 4;
    float*          A       = (float*)w;          w += (size_t)N_NODES * HID * 4;
    float*          Bf      = (float*)w;          w += (size_t)N_NODES * HID * 4;
    float*          S       = (float*)w;

    hipMemsetAsync(ecnt, 0, 256, stream);
    bucket_kernel<<<(E + 1023) / 1024, 256, 0, stream>>>(src, dst, ecnt, gedges, E);
    csr_kernel<<<NGRAPH, 256, 0, stream>>>(gedges, ecnt, rp, esorted, dinv);

    // conv1
    linear_kernel<IN_F><<<N_NODES / 64, 256, 0, stream>>>(x, W1, A);
    agg_kernel<<<NGRAPH * 8, 256, 0, stream>>>(A, esorted, rp, dinv, b1, Bf);

    // conv2
    linear_kernel<HID><<<N_NODES / 64, 256, 0, stream>>>(Bf, W2, A);
    agg_kernel<<<NGRAPH * 8, 256, 0, stream>>>(A, esorted, rp, dinv, b2, Bf);

    // DMoN pooling + classifier
    assign_kernel<<<N_NODES / 256, 256, 0, stream>>>(Bf, Wp, bp, S);
    pool_kernel<<<NGRAPH, 256, 0, stream>>>(Bf, S, Wl, bl, out);
}

// Round 5
// 297.239 us; speedup vs baseline: 3.2406x; 1.1459x over previous
//
#include <hip/hip_runtime.h>
#include <cstddef>

#define N_NODES 65536
#define NPER    1024
#define NGRAPH  64
#define HID     64
#define IN_F    128
#define KCLUS   16
#define NCLS    10
#define ECAP    18432   // per-graph edge capacity; E/NGRAPH = 16384 avg, +16 sigma

// ---------------------------------------------------------------- bucket edges by graph
__global__ __launch_bounds__(256) void bucket_kernel(const int* __restrict__ src,
                                                     const int* __restrict__ dst,
                                                     int* __restrict__ ecnt,
                                                     int* __restrict__ gedges, int E) {
    __shared__ int hist[NGRAPH];
    __shared__ int base_l[NGRAPH];
    const int t = threadIdx.x;
    const int e0 = blockIdx.x * 1024;
    if (t < NGRAPH) hist[t] = 0;
    __syncthreads();

    int gg[4], rr[4], pk[4];
#pragma unroll
    for (int i = 0; i < 4; ++i) {
        int idx = e0 + i * 256 + t;
        if (idx < E) {
            int d = dst[idx], s = src[idx];
            int g = d >> 10;
            gg[i] = g;
            pk[i] = ((d & 1023) << 10) | (s & 1023);
            rr[i] = atomicAdd(&hist[g], 1);
        } else gg[i] = -1;
    }
    __syncthreads();
    if (t < NGRAPH) base_l[t] = atomicAdd(&ecnt[t], hist[t]);
    __syncthreads();
#pragma unroll
    for (int i = 0; i < 4; ++i) {
        if (gg[i] >= 0) {
            int pos = base_l[gg[i]] + rr[i];
            if (pos < ECAP) gedges[gg[i] * ECAP + pos] = pk[i];
        }
    }
}

// ---------------------------------------------------------------- per-graph CSR build in LDS
__global__ __launch_bounds__(256) void csr_kernel(const int* __restrict__ gedges,
                                                  const int* __restrict__ ecnt,
                                                  int* __restrict__ rp,
                                                  unsigned short* __restrict__ esorted,
                                                  float* __restrict__ dinv) {
    __shared__ int hist[NPER];
    __shared__ int ts[256];
    const int g = blockIdx.x, t = threadIdx.x;
    const int ec = ecnt[g];
    const int* ge = gedges + (size_t)g * ECAP;

    for (int i = t; i < NPER; i += 256) hist[i] = 0;
    __syncthreads();
    for (int i = t; i < ec; i += 256) atomicAdd(&hist[ge[i] >> 10], 1);
    __syncthreads();

    const int b0 = t * 4;
    int h0 = hist[b0], h1 = hist[b0 + 1], h2 = hist[b0 + 2], h3 = hist[b0 + 3];
    int s0 = h0, s1 = s0 + h1, s2 = s1 + h2, s3 = s2 + h3;
    ts[t] = s3;
    __syncthreads();
    for (int off = 1; off < 256; off <<= 1) {
        int x = (t >= off) ? ts[t - off] : 0;
        __syncthreads();
        ts[t] += x;
        __syncthreads();
    }
    int excl = (t > 0) ? ts[t - 1] : 0;

    int4 o = make_int4(excl, excl + s0, excl + s1, excl + s2);
    *(int4*)(rp + g * (NPER + 1) + b0) = o;
    if (t == 255) rp[g * (NPER + 1) + NPER] = ts[255];

    float4 dv;
    dv.x = rsqrtf((float)h0 + 1.0f);
    dv.y = rsqrtf((float)h1 + 1.0f);
    dv.z = rsqrtf((float)h2 + 1.0f);
    dv.w = rsqrtf((float)h3 + 1.0f);
    *(float4*)(dinv + g * NPER + b0) = dv;

    hist[b0] = excl; hist[b0 + 1] = excl + s0; hist[b0 + 2] = excl + s1; hist[b0 + 3] = excl + s2;
    __syncthreads();

    unsigned short* es = esorted + (size_t)g * ECAP;
    for (int i = t; i < ec; i += 256) {
        int pk = ge[i];
        int pos = atomicAdd(&hist[pk >> 10], 1);
        es[pos] = (unsigned short)(pk & 1023);
    }
}

// ---------------------------------------------------------------- dense linear: Y[N,64] = X[N,K] @ W[64,K]^T
template <int K>
__global__ __launch_bounds__(256) void linear_kernel(const float* __restrict__ X,
                                                     const float* __restrict__ W,
                                                     float* __restrict__ Y) {
    __shared__ float xs[64][K + 1];
    __shared__ float ws[HID][K + 1];
    const int t = threadIdx.x;
    const size_t row0 = (size_t)blockIdx.x * 64;

    for (int i = t; i < HID * K; i += 256) ws[i / K][i % K] = W[i];
    for (int i = t; i < 64 * K; i += 256) xs[i / K][i % K] = X[row0 * K + i];
    __syncthreads();

    const int r0 = (t >> 4) * 4;
    const int c0 = (t & 15) * 4;
    float acc[4][4] = {};

#pragma unroll 4
    for (int k = 0; k < K; ++k) {
        float xv0 = xs[r0 + 0][k], xv1 = xs[r0 + 1][k];
        float xv2 = xs[r0 + 2][k], xv3 = xs[r0 + 3][k];
        float wv0 = ws[c0 + 0][k], wv1 = ws[c0 + 1][k];
        float wv2 = ws[c0 + 2][k], wv3 = ws[c0 + 3][k];
        acc[0][0] = fmaf(xv0, wv0, acc[0][0]);
        acc[0][1] = fmaf(xv0, wv1, acc[0][1]);
        acc[0][2] = fmaf(xv0, wv2, acc[0][2]);
        acc[0][3] = fmaf(xv0, wv3, acc[0][3]);
        acc[1][0] = fmaf(xv1, wv0, acc[1][0]);
        acc[1][1] = fmaf(xv1, wv1, acc[1][1]);
        acc[1][2] = fmaf(xv1, wv2, acc[1][2]);
        acc[1][3] = fmaf(xv1, wv3, acc[1][3]);
        acc[2][0] = fmaf(xv2, wv0, acc[2][0]);
        acc[2][1] = fmaf(xv2, wv1, acc[2][1]);
        acc[2][2] = fmaf(xv2, wv2, acc[2][2]);
        acc[2][3] = fmaf(xv2, wv3, acc[2][3]);
        acc[3][0] = fmaf(xv3, wv0, acc[3][0]);
        acc[3][1] = fmaf(xv3, wv1, acc[3][1]);
        acc[3][2] = fmaf(xv3, wv2, acc[3][2]);
        acc[3][3] = fmaf(xv3, wv3, acc[3][3]);
    }

#pragma unroll
    for (int i = 0; i < 4; ++i) {
        float4 v = make_float4(acc[i][0], acc[i][1], acc[i][2], acc[i][3]);
        *(float4*)(Y + (row0 + r0 + i) * HID + c0) = v;
    }
}

// ---------------------------------------------------------------- pull-based aggregation, fused self-loop+bias+relu
__global__ __launch_bounds__(256) void agg_kernel(const float* __restrict__ h,
                                                  const unsigned short* __restrict__ esorted,
                                                  const int* __restrict__ rp,
                                                  const float* __restrict__ dinv,
                                                  const float* __restrict__ bias,
                                                  float* __restrict__ outp) {
    __shared__ float Hs[8][NPER + 1];
    __shared__ float dl[NPER];
    const int g = blockIdx.x >> 3;
    const int f0 = (blockIdx.x & 7) * 8;
    const int t = threadIdx.x;
    const int base = g * NPER;

    for (int r = t; r < NPER; r += 256) {
        const float* hp = h + (size_t)(base + r) * HID + f0;
        float4 a = *(const float4*)hp;
        float4 b = *(const float4*)(hp + 4);
        float dv = dinv[base + r];
        dl[r] = dv;
        Hs[0][r] = a.x * dv; Hs[1][r] = a.y * dv; Hs[2][r] = a.z * dv; Hs[3][r] = a.w * dv;
        Hs[4][r] = b.x * dv; Hs[5][r] = b.y * dv; Hs[6][r] = b.z * dv; Hs[7][r] = b.w * dv;
    }
    float bb[8];
#pragma unroll
    for (int j = 0; j < 8; ++j) bb[j] = bias[f0 + j];
    const unsigned short* es = esorted + (size_t)g * ECAP;
    const int* rpg = rp + g * (NPER + 1);
    __syncthreads();

    for (int ld = t; ld < NPER; ld += 256) {
        int p = rpg[ld];
        const int pe = rpg[ld + 1];
        float acc[8];
#pragma unroll
        for (int j = 0; j < 8; ++j) acc[j] = Hs[j][ld];
        for (; p < pe; ++p) {
            int sl = es[p];
#pragma unroll
            for (int j = 0; j < 8; ++j) acc[j] += Hs[j][sl];
        }
        const float dv = dl[ld];
        float4 o0, o1;
        o0.x = fmaxf(fmaf(acc[0], dv, bb[0]), 0.f);
        o0.y = fmaxf(fmaf(acc[1], dv, bb[1]), 0.f);
        o0.z = fmaxf(fmaf(acc[2], dv, bb[2]), 0.f);
        o0.w = fmaxf(fmaf(acc[3], dv, bb[3]), 0.f);
        o1.x = fmaxf(fmaf(acc[4], dv, bb[4]), 0.f);
        o1.y = fmaxf(fmaf(acc[5], dv, bb[5]), 0.f);
        o1.z = fmaxf(fmaf(acc[6], dv, bb[6]), 0.f);
        o1.w = fmaxf(fmaf(acc[7], dv, bb[7]), 0.f);
        float* op = outp + (size_t)(base + ld) * HID + f0;
        *(float4*)op = o0;
        *(float4*)(op + 4) = o1;
    }
}

// ---------------------------------------------------------------- fused DMoN phase 1: softmax assignment + partial cluster sums
// grid = NGRAPH * 8; block (g, c) handles nodes [c*128, (c+1)*128) of graph g.
__global__ __launch_bounds__(256) void pool1_kernel(const float* __restrict__ h,
                                                    const float* __restrict__ Wp,
                                                    const float* __restrict__ bp,
                                                    float* __restrict__ xpart) {
    __shared__ float xs[128][HID + 1];
    __shared__ float ss[128][KCLUS + 1];
    __shared__ float wp[KCLUS][HID];
    __shared__ float bps[KCLUS];
    const int g = blockIdx.x >> 3;
    const int c = blockIdx.x & 7;
    const int t = threadIdx.x;
    const float* hb = h + ((size_t)g * NPER + c * 128) * HID;

    for (int i = t; i < 128 * HID / 4; i += 256) {
        float4 v = ((const float4*)hb)[i];
        int row = i >> 4, col = (i & 15) * 4;
        xs[row][col] = v.x; xs[row][col + 1] = v.y; xs[row][col + 2] = v.z; xs[row][col + 3] = v.w;
    }
    for (int i = t; i < KCLUS * HID; i += 256) wp[i >> 6][i & 63] = Wp[i];
    if (t < KCLUS) bps[t] = bp[t];
    __syncthreads();

    if (t < 128) {
        float lg[KCLUS];
        float mx = -1e30f;
#pragma unroll
        for (int k = 0; k < KCLUS; ++k) {
            float a = bps[k];
#pragma unroll 8
            for (int hh = 0; hh < HID; ++hh) a = fmaf(xs[t][hh], wp[k][hh], a);
            lg[k] = a;
            mx = fmaxf(mx, a);
        }
        float sum = 0.f;
#pragma unroll
        for (int k = 0; k < KCLUS; ++k) {
            lg[k] = __expf(lg[k] - mx);
            sum += lg[k];
        }
        float inv = 1.0f / sum;
#pragma unroll
        for (int k = 0; k < KCLUS; ++k) ss[t][k] = lg[k] * inv;
    }
    __syncthreads();

    const int hcol = t & 63;
    const int k0 = (t >> 6) * 4;
    float a0 = 0.f, a1 = 0.f, a2 = 0.f, a3 = 0.f;
#pragma unroll 8
    for (int n = 0; n < 128; ++n) {
        float xv = xs[n][hcol];
        a0 = fmaf(ss[n][k0 + 0], xv, a0);
        a1 = fmaf(ss[n][k0 + 1], xv, a1);
        a2 = fmaf(ss[n][k0 + 2], xv, a2);
        a3 = fmaf(ss[n][k0 + 3], xv, a3);
    }
    float* xp = xpart + (((size_t)(g * 8 + c)) * KCLUS + k0) * HID + hcol;
    xp[0] = a0; xp[HID] = a1; xp[2 * HID] = a2; xp[3 * HID] = a3;
}

// ---------------------------------------------------------------- DMoN phase 2: reduce partials, selu, mean, classifier
__global__ __launch_bounds__(256) void pool2_kernel(const float* __restrict__ xpart,
                                                    const float* __restrict__ Wl,
                                                    const float* __restrict__ bl,
                                                    float* __restrict__ out) {
    __shared__ float xp[KCLUS][HID + 1];
    __shared__ float outm[HID];
    const int g = blockIdx.x;
    const int t = threadIdx.x;
    const int hcol = t & 63;
    const int k0 = (t >> 6) * 4;
    const float* base = xpart + (size_t)g * 8 * KCLUS * HID;

    float a[4] = {};
#pragma unroll
    for (int c = 0; c < 8; ++c)
#pragma unroll
        for (int j = 0; j < 4; ++j)
            a[j] += base[(c * KCLUS + k0 + j) * HID + hcol];

    const float sc = 1.0507009873554805f, al = 1.6732632423543772f;
#pragma unroll
    for (int j = 0; j < 4; ++j) {
        float v = a[j];
        xp[k0 + j][hcol] = v > 0.f ? sc * v : sc * al * (__expf(v) - 1.f);
    }
    __syncthreads();

    if (t < HID) {
        float m = 0.f;
#pragma unroll
        for (int k = 0; k < KCLUS; ++k) m += xp[k][t];
        outm[t] = m * (1.0f / KCLUS);
    }
    __syncthreads();

    if (t < NCLS) {
        float acc = bl[t];
#pragma unroll 8
        for (int hh = 0; hh < HID; ++hh) acc = fmaf(outm[hh], Wl[t * HID + hh], acc);
        out[g * NCLS + t] = acc;
    }
}

// ---------------------------------------------------------------- launch
extern "C" void kernel_launch(void* const* d_in, const int* in_sizes, int n_in,
                              void* d_out, int out_size, void* d_ws, size_t ws_size,
                              hipStream_t stream) {
    const float* x  = (const float*)d_in[0];
    const int* eidx = (const int*)d_in[1];
    const float* W1 = (const float*)d_in[3];
    const float* b1 = (const float*)d_in[4];
    const float* W2 = (const float*)d_in[5];
    const float* b2 = (const float*)d_in[6];
    const float* Wp = (const float*)d_in[7];
    const float* bp = (const float*)d_in[8];
    const float* Wl = (const float*)d_in[9];
    const float* bl = (const float*)d_in[10];
    float* out = (float*)d_out;

    const int E = in_sizes[1] / 2;
    const int* src = eidx;
    const int* dst = eidx + E;

    // workspace layout: ecnt | gedges | esorted | rp | dinv | A | Bf | xpart
    char* w = (char*)d_ws;
    int*            ecnt    = (int*)w;            w += 256;
    int*            gedges  = (int*)w;            w += (size_t)NGRAPH * ECAP * 4;
    unsigned short* esorted = (unsigned short*)w; w += (size_t)NGRAPH * ECAP * 2;
    int*            rp      = (int*)w;            w += (size_t)NGRAPH * (NPER + 1) * 4;
    float*          dinv    = (float*)w;          w += (size_t)N_NODES * 4;
    float*          A       = (float*)w;          w += (size_t)N_NODES * HID * 4;
    float*          Bf      = (float*)w;          w += (size_t)N_NODES * HID * 4;
    float*          xpart   = (float*)w;          w += (size_t)NGRAPH * 8 * KCLUS * HID * 4;

    hipMemsetAsync(ecnt, 0, 256, stream);
    bucket_kernel<<<(E + 1023) / 1024, 256, 0, stream>>>(src, dst, ecnt, gedges, E);
    csr_kernel<<<NGRAPH, 256, 0, stream>>>(gedges, ecnt, rp, esorted, dinv);

    // conv1
    linear_kernel<IN_F><<<N_NODES / 64, 256, 0, stream>>>(x, W1, A);
    agg_kernel<<<NGRAPH * 8, 256, 0, stream>>>(A, esorted, rp, dinv, b1, Bf);

    // conv2
    linear_kernel<HID><<<N_NODES / 64, 256, 0, stream>>>(Bf, W2, A);
    agg_kernel<<<NGRAPH * 8, 256, 0, stream>>>(A, esorted, rp, dinv, b2, Bf);

    // DMoN pooling + classifier (fused softmax into pool1)
    pool1_kernel<<<NGRAPH * 8, 256, 0, stream>>>(Bf, Wp, bp, xpart);
    pool2_kernel<<<NGRAPH, 256, 0, stream>>>(xpart, Wl, bl, out);
}

// Round 6
// 268.123 us; speedup vs baseline: 3.5925x; 1.1086x over previous
//
#include <hip/hip_runtime.h>
#include <cstddef>

#define N_NODES 65536
#define NPER    1024
#define NGRAPH  64
#define HID     64
#define IN_F    128
#define KCLUS   16
#define NCLS    10
#define ECAP    18432   // per-graph edge capacity; E/NGRAPH = 16384 avg, +16 sigma

// ---------------------------------------------------------------- bucket edges by graph
__global__ __launch_bounds__(256) void bucket_kernel(const int* __restrict__ src,
                                                     const int* __restrict__ dst,
                                                     int* __restrict__ ecnt,
                                                     int* __restrict__ gedges, int E) {
    __shared__ int hist[NGRAPH];
    __shared__ int base_l[NGRAPH];
    const int t = threadIdx.x;
    const int e0 = blockIdx.x * 1024;
    if (t < NGRAPH) hist[t] = 0;
    __syncthreads();

    int gg[4], rr[4], pk[4];
#pragma unroll
    for (int i = 0; i < 4; ++i) {
        int idx = e0 + i * 256 + t;
        if (idx < E) {
            int d = dst[idx], s = src[idx];
            int g = d >> 10;
            gg[i] = g;
            pk[i] = ((d & 1023) << 10) | (s & 1023);
            rr[i] = atomicAdd(&hist[g], 1);
        } else gg[i] = -1;
    }
    __syncthreads();
    if (t < NGRAPH) base_l[t] = atomicAdd(&ecnt[t], hist[t]);
    __syncthreads();
#pragma unroll
    for (int i = 0; i < 4; ++i) {
        if (gg[i] >= 0) {
            int pos = base_l[gg[i]] + rr[i];
            if (pos < ECAP) gedges[gg[i] * ECAP + pos] = pk[i];
        }
    }
}

// ---------------------------------------------------------------- per-graph CSR build in LDS (1024 thr: 16 waves on each active CU)
__global__ __launch_bounds__(1024) void csr_kernel(const int* __restrict__ gedges,
                                                   const int* __restrict__ ecnt,
                                                   int* __restrict__ rp,
                                                   unsigned short* __restrict__ esorted,
                                                   float* __restrict__ dinv) {
    __shared__ int hist[NPER];
    __shared__ int ts[NPER];
    const int g = blockIdx.x, t = threadIdx.x;
    const int ec = ecnt[g];
    const int* ge = gedges + (size_t)g * ECAP;

    hist[t] = 0;
    __syncthreads();
    for (int i = t; i < ec; i += 1024) atomicAdd(&hist[ge[i] >> 10], 1);
    __syncthreads();

    const int h0 = hist[t];
    ts[t] = h0;
    __syncthreads();
    for (int off = 1; off < 1024; off <<= 1) {
        int x = (t >= off) ? ts[t - off] : 0;
        __syncthreads();
        ts[t] += x;
        __syncthreads();
    }
    const int excl = ts[t] - h0;

    rp[g * (NPER + 1) + t] = excl;
    if (t == NPER - 1) rp[g * (NPER + 1) + NPER] = ts[t];
    dinv[g * NPER + t] = rsqrtf((float)h0 + 1.0f);

    hist[t] = excl;   // reuse as scatter cursor
    __syncthreads();

    unsigned short* es = esorted + (size_t)g * ECAP;
    for (int i = t; i < ec; i += 1024) {
        int pk = ge[i];
        int pos = atomicAdd(&hist[pk >> 10], 1);
        es[pos] = (unsigned short)(pk & 1023);
    }
}

// ---------------------------------------------------------------- dense linear: Y[N,64] = X[N,K] @ W[64,K]^T
template <int K>
__global__ __launch_bounds__(256) void linear_kernel(const float* __restrict__ X,
                                                     const float* __restrict__ W,
                                                     float* __restrict__ Y) {
    __shared__ float xs[64][K + 1];
    __shared__ float ws[HID][K + 1];
    const int t = threadIdx.x;
    const size_t row0 = (size_t)blockIdx.x * 64;

    for (int i = t; i < HID * K; i += 256) ws[i / K][i % K] = W[i];
    for (int i = t; i < 64 * K; i += 256) xs[i / K][i % K] = X[row0 * K + i];
    __syncthreads();

    const int r0 = (t >> 4) * 4;
    const int c0 = (t & 15) * 4;
    float acc[4][4] = {};

#pragma unroll 4
    for (int k = 0; k < K; ++k) {
        float xv0 = xs[r0 + 0][k], xv1 = xs[r0 + 1][k];
        float xv2 = xs[r0 + 2][k], xv3 = xs[r0 + 3][k];
        float wv0 = ws[c0 + 0][k], wv1 = ws[c0 + 1][k];
        float wv2 = ws[c0 + 2][k], wv3 = ws[c0 + 3][k];
        acc[0][0] = fmaf(xv0, wv0, acc[0][0]);
        acc[0][1] = fmaf(xv0, wv1, acc[0][1]);
        acc[0][2] = fmaf(xv0, wv2, acc[0][2]);
        acc[0][3] = fmaf(xv0, wv3, acc[0][3]);
        acc[1][0] = fmaf(xv1, wv0, acc[1][0]);
        acc[1][1] = fmaf(xv1, wv1, acc[1][1]);
        acc[1][2] = fmaf(xv1, wv2, acc[1][2]);
        acc[1][3] = fmaf(xv1, wv3, acc[1][3]);
        acc[2][0] = fmaf(xv2, wv0, acc[2][0]);
        acc[2][1] = fmaf(xv2, wv1, acc[2][1]);
        acc[2][2] = fmaf(xv2, wv2, acc[2][2]);
        acc[2][3] = fmaf(xv2, wv3, acc[2][3]);
        acc[3][0] = fmaf(xv3, wv0, acc[3][0]);
        acc[3][1] = fmaf(xv3, wv1, acc[3][1]);
        acc[3][2] = fmaf(xv3, wv2, acc[3][2]);
        acc[3][3] = fmaf(xv3, wv3, acc[3][3]);
    }

#pragma unroll
    for (int i = 0; i < 4; ++i) {
        float4 v = make_float4(acc[i][0], acc[i][1], acc[i][2], acc[i][3]);
        *(float4*)(Y + (row0 + r0 + i) * HID + c0) = v;
    }
}

// ---------------------------------------------------------------- pull-based aggregation, fused self-loop+bias+relu
// 512 threads: 2 blocks/CU (37 KB LDS) -> 16 waves/CU for latency hiding.
__global__ __launch_bounds__(512) void agg_kernel(const float* __restrict__ h,
                                                  const unsigned short* __restrict__ esorted,
                                                  const int* __restrict__ rp,
                                                  const float* __restrict__ dinv,
                                                  const float* __restrict__ bias,
                                                  float* __restrict__ outp) {
    __shared__ float Hs[8][NPER + 1];
    __shared__ float dl[NPER];
    const int g = blockIdx.x >> 3;
    const int f0 = (blockIdx.x & 7) * 8;
    const int t = threadIdx.x;
    const int base = g * NPER;

    for (int r = t; r < NPER; r += 512) {
        const float* hp = h + (size_t)(base + r) * HID + f0;
        float4 a = *(const float4*)hp;
        float4 b = *(const float4*)(hp + 4);
        float dv = dinv[base + r];
        dl[r] = dv;
        Hs[0][r] = a.x * dv; Hs[1][r] = a.y * dv; Hs[2][r] = a.z * dv; Hs[3][r] = a.w * dv;
        Hs[4][r] = b.x * dv; Hs[5][r] = b.y * dv; Hs[6][r] = b.z * dv; Hs[7][r] = b.w * dv;
    }
    float bb[8];
#pragma unroll
    for (int j = 0; j < 8; ++j) bb[j] = bias[f0 + j];
    const unsigned short* es = esorted + (size_t)g * ECAP;
    const int* rpg = rp + g * (NPER + 1);
    __syncthreads();

    for (int ld = t; ld < NPER; ld += 512) {
        int p = rpg[ld];
        const int pe = rpg[ld + 1];
        float acc[8];
#pragma unroll
        for (int j = 0; j < 8; ++j) acc[j] = Hs[j][ld];
        for (; p < pe; ++p) {
            int sl = es[p];
#pragma unroll
            for (int j = 0; j < 8; ++j) acc[j] += Hs[j][sl];
        }
        const float dv = dl[ld];
        float4 o0, o1;
        o0.x = fmaxf(fmaf(acc[0], dv, bb[0]), 0.f);
        o0.y = fmaxf(fmaf(acc[1], dv, bb[1]), 0.f);
        o0.z = fmaxf(fmaf(acc[2], dv, bb[2]), 0.f);
        o0.w = fmaxf(fmaf(acc[3], dv, bb[3]), 0.f);
        o1.x = fmaxf(fmaf(acc[4], dv, bb[4]), 0.f);
        o1.y = fmaxf(fmaf(acc[5], dv, bb[5]), 0.f);
        o1.z = fmaxf(fmaf(acc[6], dv, bb[6]), 0.f);
        o1.w = fmaxf(fmaf(acc[7], dv, bb[7]), 0.f);
        float* op = outp + (size_t)(base + ld) * HID + f0;
        *(float4*)op = o0;
        *(float4*)(op + 4) = o1;
    }
}

// ---------------------------------------------------------------- fused DMoN phase 1: softmax assignment + partial cluster sums
__global__ __launch_bounds__(256) void pool1_kernel(const float* __restrict__ h,
                                                    const float* __restrict__ Wp,
                                                    const float* __restrict__ bp,
                                                    float* __restrict__ xpart) {
    __shared__ float xs[128][HID + 1];
    __shared__ float ss[128][KCLUS + 1];
    __shared__ float wp[KCLUS][HID];
    __shared__ float bps[KCLUS];
    const int g = blockIdx.x >> 3;
    const int c = blockIdx.x & 7;
    const int t = threadIdx.x;
    const float* hb = h + ((size_t)g * NPER + c * 128) * HID;

    for (int i = t; i < 128 * HID / 4; i += 256) {
        float4 v = ((const float4*)hb)[i];
        int row = i >> 4, col = (i & 15) * 4;
        xs[row][col] = v.x; xs[row][col + 1] = v.y; xs[row][col + 2] = v.z; xs[row][col + 3] = v.w;
    }
    for (int i = t; i < KCLUS * HID; i += 256) wp[i >> 6][i & 63] = Wp[i];
    if (t < KCLUS) bps[t] = bp[t];
    __syncthreads();

    if (t < 128) {
        float lg[KCLUS];
        float mx = -1e30f;
#pragma unroll
        for (int k = 0; k < KCLUS; ++k) {
            float a = bps[k];
#pragma unroll 8
            for (int hh = 0; hh < HID; ++hh) a = fmaf(xs[t][hh], wp[k][hh], a);
            lg[k] = a;
            mx = fmaxf(mx, a);
        }
        float sum = 0.f;
#pragma unroll
        for (int k = 0; k < KCLUS; ++k) {
            lg[k] = __expf(lg[k] - mx);
            sum += lg[k];
        }
        float inv = 1.0f / sum;
#pragma unroll
        for (int k = 0; k < KCLUS; ++k) ss[t][k] = lg[k] * inv;
    }
    __syncthreads();

    const int hcol = t & 63;
    const int k0 = (t >> 6) * 4;
    float a0 = 0.f, a1 = 0.f, a2 = 0.f, a3 = 0.f;
#pragma unroll 8
    for (int n = 0; n < 128; ++n) {
        float xv = xs[n][hcol];
        a0 = fmaf(ss[n][k0 + 0], xv, a0);
        a1 = fmaf(ss[n][k0 + 1], xv, a1);
        a2 = fmaf(ss[n][k0 + 2], xv, a2);
        a3 = fmaf(ss[n][k0 + 3], xv, a3);
    }
    float* xp = xpart + (((size_t)(g * 8 + c)) * KCLUS + k0) * HID + hcol;
    xp[0] = a0; xp[HID] = a1; xp[2 * HID] = a2; xp[3 * HID] = a3;
}

// ---------------------------------------------------------------- DMoN phase 2: reduce partials, selu, mean, classifier
__global__ __launch_bounds__(256) void pool2_kernel(const float* __restrict__ xpart,
                                                    const float* __restrict__ Wl,
                                                    const float* __restrict__ bl,
                                                    float* __restrict__ out) {
    __shared__ float xp[KCLUS][HID + 1];
    __shared__ float outm[HID];
    const int g = blockIdx.x;
    const int t = threadIdx.x;
    const int hcol = t & 63;
    const int k0 = (t >> 6) * 4;
    const float* base = xpart + (size_t)g * 8 * KCLUS * HID;

    float a[4] = {};
#pragma unroll
    for (int c = 0; c < 8; ++c)
#pragma unroll
        for (int j = 0; j < 4; ++j)
            a[j] += base[(c * KCLUS + k0 + j) * HID + hcol];

    const float sc = 1.0507009873554805f, al = 1.6732632423543772f;
#pragma unroll
    for (int j = 0; j < 4; ++j) {
        float v = a[j];
        xp[k0 + j][hcol] = v > 0.f ? sc * v : sc * al * (__expf(v) - 1.f);
    }
    __syncthreads();

    if (t < HID) {
        float m = 0.f;
#pragma unroll
        for (int k = 0; k < KCLUS; ++k) m += xp[k][t];
        outm[t] = m * (1.0f / KCLUS);
    }
    __syncthreads();

    if (t < NCLS) {
        float acc = bl[t];
#pragma unroll 8
        for (int hh = 0; hh < HID; ++hh) acc = fmaf(outm[hh], Wl[t * HID + hh], acc);
        out[g * NCLS + t] = acc;
    }
}

// ---------------------------------------------------------------- launch
extern "C" void kernel_launch(void* const* d_in, const int* in_sizes, int n_in,
                              void* d_out, int out_size, void* d_ws, size_t ws_size,
                              hipStream_t stream) {
    const float* x  = (const float*)d_in[0];
    const int* eidx = (const int*)d_in[1];
    const float* W1 = (const float*)d_in[3];
    const float* b1 = (const float*)d_in[4];
    const float* W2 = (const float*)d_in[5];
    const float* b2 = (const float*)d_in[6];
    const float* Wp = (const float*)d_in[7];
    const float* bp = (const float*)d_in[8];
    const float* Wl = (const float*)d_in[9];
    const float* bl = (const float*)d_in[10];
    float* out = (float*)d_out;

    const int E = in_sizes[1] / 2;
    const int* src = eidx;
    const int* dst = eidx + E;

    // workspace layout: ecnt | gedges | esorted | rp | dinv | A | Bf | xpart
    char* w = (char*)d_ws;
    int*            ecnt    = (int*)w;            w += 256;
    int*            gedges  = (int*)w;            w += (size_t)NGRAPH * ECAP * 4;
    unsigned short* esorted = (unsigned short*)w; w += (size_t)NGRAPH * ECAP * 2;
    int*            rp      = (int*)w;            w += (size_t)NGRAPH * (NPER + 1) * 4;
    float*          dinv    = (float*)w;          w += (size_t)N_NODES * 4;
    float*          A       = (float*)w;          w += (size_t)N_NODES * HID * 4;
    float*          Bf      = (float*)w;          w += (size_t)N_NODES * HID * 4;
    float*          xpart   = (float*)w;          w += (size_t)NGRAPH * 8 * KCLUS * HID * 4;

    hipMemsetAsync(ecnt, 0, 256, stream);
    bucket_kernel<<<(E + 1023) / 1024, 256, 0, stream>>>(src, dst, ecnt, gedges, E);
    csr_kernel<<<NGRAPH, 1024, 0, stream>>>(gedges, ecnt, rp, esorted, dinv);

    // conv1
    linear_kernel<IN_F><<<N_NODES / 64, 256, 0, stream>>>(x, W1, A);
    agg_kernel<<<NGRAPH * 8, 512, 0, stream>>>(A, esorted, rp, dinv, b1, Bf);

    // conv2
    linear_kernel<HID><<<N_NODES / 64, 256, 0, stream>>>(Bf, W2, A);
    agg_kernel<<<NGRAPH * 8, 512, 0, stream>>>(A, esorted, rp, dinv, b2, Bf);

    // DMoN pooling + classifier
    pool1_kernel<<<NGRAPH * 8, 256, 0, stream>>>(Bf, Wp, bp, xpart);
    pool2_kernel<<<NGRAPH, 256, 0, stream>>>(xpart, Wl, bl, out);
}

// Round 7
// 256.785 us; speedup vs baseline: 3.7511x; 1.0442x over previous
//
#include <hip/hip_runtime.h>
#include <cstddef>

#define N_NODES 65536
#define NPER    1024
#define NGRAPH  64
#define HID     64
#define IN_F    128
#define KCLUS   16
#define NCLS    10
#define ECAP    18432   // per-graph edge capacity; E/NGRAPH = 16384 avg, +16 sigma

// ---------------------------------------------------------------- bucket edges by graph
__global__ __launch_bounds__(256) void bucket_kernel(const int* __restrict__ src,
                                                     const int* __restrict__ dst,
                                                     int* __restrict__ ecnt,
                                                     int* __restrict__ gedges, int E) {
    __shared__ int hist[NGRAPH];
    __shared__ int base_l[NGRAPH];
    const int t = threadIdx.x;
    const int e0 = blockIdx.x * 1024;
    if (t < NGRAPH) hist[t] = 0;
    __syncthreads();

    int gg[4], rr[4], pk[4];
#pragma unroll
    for (int i = 0; i < 4; ++i) {
        int idx = e0 + i * 256 + t;
        if (idx < E) {
            int d = dst[idx], s = src[idx];
            int g = d >> 10;
            gg[i] = g;
            pk[i] = ((d & 1023) << 10) | (s & 1023);
            rr[i] = atomicAdd(&hist[g], 1);
        } else gg[i] = -1;
    }
    __syncthreads();
    if (t < NGRAPH) base_l[t] = atomicAdd(&ecnt[t], hist[t]);
    __syncthreads();
#pragma unroll
    for (int i = 0; i < 4; ++i) {
        if (gg[i] >= 0) {
            int pos = base_l[gg[i]] + rr[i];
            if (pos < ECAP) gedges[gg[i] * ECAP + pos] = pk[i];
        }
    }
}

// ---------------------------------------------------------------- per-graph CSR build in LDS
__global__ __launch_bounds__(1024) void csr_kernel(const int* __restrict__ gedges,
                                                   const int* __restrict__ ecnt,
                                                   int* __restrict__ rp,
                                                   unsigned short* __restrict__ esorted,
                                                   float* __restrict__ dinv) {
    __shared__ int hist[NPER];
    __shared__ int ts[NPER];
    const int g = blockIdx.x, t = threadIdx.x;
    const int ec = ecnt[g];
    const int* ge = gedges + (size_t)g * ECAP;

    hist[t] = 0;
    __syncthreads();
    for (int i = t; i < ec; i += 1024) atomicAdd(&hist[ge[i] >> 10], 1);
    __syncthreads();

    const int h0 = hist[t];
    ts[t] = h0;
    __syncthreads();
    for (int off = 1; off < 1024; off <<= 1) {
        int x = (t >= off) ? ts[t - off] : 0;
        __syncthreads();
        ts[t] += x;
        __syncthreads();
    }
    const int excl = ts[t] - h0;

    rp[g * (NPER + 1) + t] = excl;
    if (t == NPER - 1) rp[g * (NPER + 1) + NPER] = ts[t];
    dinv[g * NPER + t] = rsqrtf((float)h0 + 1.0f);

    hist[t] = excl;   // reuse as scatter cursor
    __syncthreads();

    unsigned short* es = esorted + (size_t)g * ECAP;
    for (int i = t; i < ec; i += 1024) {
        int pk = ge[i];
        int pos = atomicAdd(&hist[pk >> 10], 1);
        es[pos] = (unsigned short)(pk & 1023);
    }
}

// ---------------------------------------------------------------- dense linear: Y[N,64] = X[N,K] @ W[64,K]^T
// Transposed-LDS layout: xsT[k][row], wsT[k][col] so the inner loop is
// 2x ds_read_b128 per 16 fma (FMA-bound, not LDS-bound). K tiled by 64.
template <int K>
__global__ __launch_bounds__(256) void linear_kernel(const float* __restrict__ X,
                                                     const float* __restrict__ W,
                                                     float* __restrict__ Y) {
    __shared__ float xsT[64][68];
    __shared__ float wsT[64][68];
    const int t = threadIdx.x;
    const size_t row0 = (size_t)blockIdx.x * 64;
    const int r0 = (t >> 4) * 4;
    const int c0 = (t & 15) * 4;
    float acc[4][4] = {};

    for (int kc = 0; kc < K; kc += 64) {
        __syncthreads();
        for (int i = t; i < 1024; i += 256) {         // 64 rows x 64 k of X
            int row = i >> 4, k4 = (i & 15) << 2;
            float4 v = *(const float4*)(X + (row0 + row) * K + kc + k4);
            xsT[k4 + 0][row] = v.x;
            xsT[k4 + 1][row] = v.y;
            xsT[k4 + 2][row] = v.z;
            xsT[k4 + 3][row] = v.w;
        }
        for (int i = t; i < 1024; i += 256) {         // 64 cols x 64 k of W
            int col = i >> 4, k4 = (i & 15) << 2;
            float4 v = *(const float4*)(W + col * K + kc + k4);
            wsT[k4 + 0][col] = v.x;
            wsT[k4 + 1][col] = v.y;
            wsT[k4 + 2][col] = v.z;
            wsT[k4 + 3][col] = v.w;
        }
        __syncthreads();

#pragma unroll 8
        for (int k = 0; k < 64; ++k) {
            float4 xv = *(const float4*)&xsT[k][r0];
            float4 wv = *(const float4*)&wsT[k][c0];
            acc[0][0] = fmaf(xv.x, wv.x, acc[0][0]);
            acc[0][1] = fmaf(xv.x, wv.y, acc[0][1]);
            acc[0][2] = fmaf(xv.x, wv.z, acc[0][2]);
            acc[0][3] = fmaf(xv.x, wv.w, acc[0][3]);
            acc[1][0] = fmaf(xv.y, wv.x, acc[1][0]);
            acc[1][1] = fmaf(xv.y, wv.y, acc[1][1]);
            acc[1][2] = fmaf(xv.y, wv.z, acc[1][2]);
            acc[1][3] = fmaf(xv.y, wv.w, acc[1][3]);
            acc[2][0] = fmaf(xv.z, wv.x, acc[2][0]);
            acc[2][1] = fmaf(xv.z, wv.y, acc[2][1]);
            acc[2][2] = fmaf(xv.z, wv.z, acc[2][2]);
            acc[2][3] = fmaf(xv.z, wv.w, acc[2][3]);
            acc[3][0] = fmaf(xv.w, wv.x, acc[3][0]);
            acc[3][1] = fmaf(xv.w, wv.y, acc[3][1]);
            acc[3][2] = fmaf(xv.w, wv.z, acc[3][2]);
            acc[3][3] = fmaf(xv.w, wv.w, acc[3][3]);
        }
    }

#pragma unroll
    for (int i = 0; i < 4; ++i) {
        float4 v = make_float4(acc[i][0], acc[i][1], acc[i][2], acc[i][3]);
        *(float4*)(Y + (row0 + r0 + i) * HID + c0) = v;
    }
}

// ---------------------------------------------------------------- pull-based aggregation, fused self-loop+bias+relu
__global__ __launch_bounds__(512) void agg_kernel(const float* __restrict__ h,
                                                  const unsigned short* __restrict__ esorted,
                                                  const int* __restrict__ rp,
                                                  const float* __restrict__ dinv,
                                                  const float* __restrict__ bias,
                                                  float* __restrict__ outp) {
    __shared__ float Hs[8][NPER + 1];
    __shared__ float dl[NPER];
    const int g = blockIdx.x >> 3;
    const int f0 = (blockIdx.x & 7) * 8;
    const int t = threadIdx.x;
    const int base = g * NPER;

    for (int r = t; r < NPER; r += 512) {
        const float* hp = h + (size_t)(base + r) * HID + f0;
        float4 a = *(const float4*)hp;
        float4 b = *(const float4*)(hp + 4);
        float dv = dinv[base + r];
        dl[r] = dv;
        Hs[0][r] = a.x * dv; Hs[1][r] = a.y * dv; Hs[2][r] = a.z * dv; Hs[3][r] = a.w * dv;
        Hs[4][r] = b.x * dv; Hs[5][r] = b.y * dv; Hs[6][r] = b.z * dv; Hs[7][r] = b.w * dv;
    }
    float bb[8];
#pragma unroll
    for (int j = 0; j < 8; ++j) bb[j] = bias[f0 + j];
    const unsigned short* es = esorted + (size_t)g * ECAP;
    const int* rpg = rp + g * (NPER + 1);
    __syncthreads();

    for (int ld = t; ld < NPER; ld += 512) {
        int p = rpg[ld];
        const int pe = rpg[ld + 1];
        float acc[8];
#pragma unroll
        for (int j = 0; j < 8; ++j) acc[j] = Hs[j][ld];
        for (; p < pe; ++p) {
            int sl = es[p];
#pragma unroll
            for (int j = 0; j < 8; ++j) acc[j] += Hs[j][sl];
        }
        const float dv = dl[ld];
        float4 o0, o1;
        o0.x = fmaxf(fmaf(acc[0], dv, bb[0]), 0.f);
        o0.y = fmaxf(fmaf(acc[1], dv, bb[1]), 0.f);
        o0.z = fmaxf(fmaf(acc[2], dv, bb[2]), 0.f);
        o0.w = fmaxf(fmaf(acc[3], dv, bb[3]), 0.f);
        o1.x = fmaxf(fmaf(acc[4], dv, bb[4]), 0.f);
        o1.y = fmaxf(fmaf(acc[5], dv, bb[5]), 0.f);
        o1.z = fmaxf(fmaf(acc[6], dv, bb[6]), 0.f);
        o1.w = fmaxf(fmaf(acc[7], dv, bb[7]), 0.f);
        float* op = outp + (size_t)(base + ld) * HID + f0;
        *(float4*)op = o0;
        *(float4*)(op + 4) = o1;
    }
}

// ---------------------------------------------------------------- fused DMoN phase 1: softmax assignment + partial cluster sums
__global__ __launch_bounds__(256) void pool1_kernel(const float* __restrict__ h,
                                                    const float* __restrict__ Wp,
                                                    const float* __restrict__ bp,
                                                    float* __restrict__ xpart) {
    __shared__ float xs[128][HID + 1];
    __shared__ float ss[128][KCLUS + 1];
    __shared__ float wp[KCLUS][HID];
    __shared__ float bps[KCLUS];
    const int g = blockIdx.x >> 3;
    const int c = blockIdx.x & 7;
    const int t = threadIdx.x;
    const float* hb = h + ((size_t)g * NPER + c * 128) * HID;

    for (int i = t; i < 128 * HID / 4; i += 256) {
        float4 v = ((const float4*)hb)[i];
        int row = i >> 4, col = (i & 15) * 4;
        xs[row][col] = v.x; xs[row][col + 1] = v.y; xs[row][col + 2] = v.z; xs[row][col + 3] = v.w;
    }
    for (int i = t; i < KCLUS * HID; i += 256) wp[i >> 6][i & 63] = Wp[i];
    if (t < KCLUS) bps[t] = bp[t];
    __syncthreads();

    if (t < 128) {
        float lg[KCLUS];
        float mx = -1e30f;
#pragma unroll
        for (int k = 0; k < KCLUS; ++k) {
            float a = bps[k];
#pragma unroll 8
            for (int hh = 0; hh < HID; ++hh) a = fmaf(xs[t][hh], wp[k][hh], a);
            lg[k] = a;
            mx = fmaxf(mx, a);
        }
        float sum = 0.f;
#pragma unroll
        for (int k = 0; k < KCLUS; ++k) {
            lg[k] = __expf(lg[k] - mx);
            sum += lg[k];
        }
        float inv = 1.0f / sum;
#pragma unroll
        for (int k = 0; k < KCLUS; ++k) ss[t][k] = lg[k] * inv;
    }
    __syncthreads();

    const int hcol = t & 63;
    const int k0 = (t >> 6) * 4;
    float a0 = 0.f, a1 = 0.f, a2 = 0.f, a3 = 0.f;
#pragma unroll 8
    for (int n = 0; n < 128; ++n) {
        float xv = xs[n][hcol];
        a0 = fmaf(ss[n][k0 + 0], xv, a0);
        a1 = fmaf(ss[n][k0 + 1], xv, a1);
        a2 = fmaf(ss[n][k0 + 2], xv, a2);
        a3 = fmaf(ss[n][k0 + 3], xv, a3);
    }
    float* xp = xpart + (((size_t)(g * 8 + c)) * KCLUS + k0) * HID + hcol;
    xp[0] = a0; xp[HID] = a1; xp[2 * HID] = a2; xp[3 * HID] = a3;
}

// ---------------------------------------------------------------- DMoN phase 2: reduce partials, selu, mean, classifier
__global__ __launch_bounds__(256) void pool2_kernel(const float* __restrict__ xpart,
                                                    const float* __restrict__ Wl,
                                                    const float* __restrict__ bl,
                                                    float* __restrict__ out) {
    __shared__ float xp[KCLUS][HID + 1];
    __shared__ float outm[HID];
    const int g = blockIdx.x;
    const int t = threadIdx.x;
    const int hcol = t & 63;
    const int k0 = (t >> 6) * 4;
    const float* base = xpart + (size_t)g * 8 * KCLUS * HID;

    float a[4] = {};
#pragma unroll
    for (int c = 0; c < 8; ++c)
#pragma unroll
        for (int j = 0; j < 4; ++j)
            a[j] += base[(c * KCLUS + k0 + j) * HID + hcol];

    const float sc = 1.0507009873554805f, al = 1.6732632423543772f;
#pragma unroll
    for (int j = 0; j < 4; ++j) {
        float v = a[j];
        xp[k0 + j][hcol] = v > 0.f ? sc * v : sc * al * (__expf(v) - 1.f);
    }
    __syncthreads();

    if (t < HID) {
        float m = 0.f;
#pragma unroll
        for (int k = 0; k < KCLUS; ++k) m += xp[k][t];
        outm[t] = m * (1.0f / KCLUS);
    }
    __syncthreads();

    if (t < NCLS) {
        float acc = bl[t];
#pragma unroll 8
        for (int hh = 0; hh < HID; ++hh) acc = fmaf(outm[hh], Wl[t * HID + hh], acc);
        out[g * NCLS + t] = acc;
    }
}

// ---------------------------------------------------------------- launch
extern "C" void kernel_launch(void* const* d_in, const int* in_sizes, int n_in,
                              void* d_out, int out_size, void* d_ws, size_t ws_size,
                              hipStream_t stream) {
    const float* x  = (const float*)d_in[0];
    const int* eidx = (const int*)d_in[1];
    const float* W1 = (const float*)d_in[3];
    const float* b1 = (const float*)d_in[4];
    const float* W2 = (const float*)d_in[5];
    const float* b2 = (const float*)d_in[6];
    const float* Wp = (const float*)d_in[7];
    const float* bp = (const float*)d_in[8];
    const float* Wl = (const float*)d_in[9];
    const float* bl = (const float*)d_in[10];
    float* out = (float*)d_out;

    const int E = in_sizes[1] / 2;
    const int* src = eidx;
    const int* dst = eidx + E;

    // workspace layout: ecnt | gedges | esorted | rp | dinv | A | Bf | xpart
    char* w = (char*)d_ws;
    int*            ecnt    = (int*)w;            w += 256;
    int*            gedges  = (int*)w;            w += (size_t)NGRAPH * ECAP * 4;
    unsigned short* esorted = (unsigned short*)w; w += (size_t)NGRAPH * ECAP * 2;
    int*            rp      = (int*)w;            w += (size_t)NGRAPH * (NPER + 1) * 4;
    float*          dinv    = (float*)w;          w += (size_t)N_NODES * 4;
    float*          A       = (float*)w;          w += (size_t)N_NODES * HID * 4;
    float*          Bf      = (float*)w;          w += (size_t)N_NODES * HID * 4;
    float*          xpart   = (float*)w;          w += (size_t)NGRAPH * 8 * KCLUS * HID * 4;

    hipMemsetAsync(ecnt, 0, 256, stream);
    bucket_kernel<<<(E + 1023) / 1024, 256, 0, stream>>>(src, dst, ecnt, gedges, E);
    csr_kernel<<<NGRAPH, 1024, 0, stream>>>(gedges, ecnt, rp, esorted, dinv);

    // conv1
    linear_kernel<IN_F><<<N_NODES / 64, 256, 0, stream>>>(x, W1, A);
    agg_kernel<<<NGRAPH * 8, 512, 0, stream>>>(A, esorted, rp, dinv, b1, Bf);

    // conv2
    linear_kernel<HID><<<N_NODES / 64, 256, 0, stream>>>(Bf, W2, A);
    agg_kernel<<<NGRAPH * 8, 512, 0, stream>>>(A, esorted, rp, dinv, b2, Bf);

    // DMoN pooling + classifier
    pool1_kernel<<<NGRAPH * 8, 256, 0, stream>>>(Bf, Wp, bp, xpart);
    pool2_kernel<<<NGRAPH, 256, 0, stream>>>(xpart, Wl, bl, out);
}